// Round 3
// baseline (362.021 us; speedup 1.0000x reference)
//
#include <hip/hip_runtime.h>
#include <stdint.h>

#define NPTS 131072
#define CINC 128
#define COUTC 128
#define WDIM 512
#define K3 27

typedef float f32x4 __attribute__((ext_vector_type(4)));
typedef __bf16 bf16x8 __attribute__((ext_vector_type(8)));

#define GLOAD_LDS16(g, l) \
  __builtin_amdgcn_global_load_lds((const __attribute__((address_space(1))) void*)(g), \
                                   (__attribute__((address_space(3))) void*)(l), 16, 0, 0)

__device__ __forceinline__ unsigned short f2bf(float x){
  union { float f; uint32_t u; } v; v.f = x;
  uint32_t u = v.u;
  uint32_t r = (u + 0x7fffu + ((u >> 16) & 1u)) >> 16;
  return (unsigned short)r;
}

// styles[b*128+c] = dot(w[b], aw[c])/sqrt(512) + ab[c]; 4 dots/block, 1/wave
__global__ void k_styles_dot(const float* __restrict__ w, const float* __restrict__ aw,
                             const float* __restrict__ ab, float* __restrict__ styles){
  int wave = threadIdx.x >> 6, lane = threadIdx.x & 63;
  int blk = blockIdx.x * 4 + wave;            // 512 dots
  int b = blk >> 7, c = blk & 127;
  const float4* wr = (const float4*)(w + b * WDIM);
  const float4* ar = (const float4*)(aw + c * WDIM);
  float4 w0 = wr[lane * 2], w1 = wr[lane * 2 + 1];
  float4 a0 = ar[lane * 2], a1 = ar[lane * 2 + 1];
  float s = w0.x * a0.x + w0.y * a0.y + w0.z * a0.z + w0.w * a0.w
          + w1.x * a1.x + w1.y * a1.y + w1.z * a1.z + w1.w * a1.w;
  for (int off = 32; off > 0; off >>= 1) s += __shfl_down(s, off, 64);
  if (lane == 0) styles[blk] = s * 0.04419417382415922f + ab[c];
}

// merged snorm + dcoefs2: every block redundantly reduces styles^2 (2KB), then
// wave w computes dco2 for pair = blk*8+w; block 0 additionally writes sn[].
__global__ void k_sn_dco(const float* __restrict__ styles, const float* __restrict__ vmat,
                         const float* __restrict__ wnorm, const float* __restrict__ mag,
                         float* __restrict__ sn, float* __restrict__ dco2){
  __shared__ float red[512];
  int t = threadIdx.x;
  float s = styles[t];
  red[t] = s * s;
  __syncthreads();
  for (int off = 256; off > 0; off >>= 1){
    if (t < off) red[t] += red[t + off];
    __syncthreads();
  }
  float rs = rsqrtf(red[0] * (1.0f / 512.0f));
  if (blockIdx.x == 0) sn[t] = s * rs;
  int wave = t >> 6, lane = t & 63;
  int pair = blockIdx.x * 8 + wave;          // b*128+co
  int b = pair >> 7, co = pair & 127;
  float s0 = styles[b * 128 + lane] * rs, s1 = styles[b * 128 + 64 + lane] * rs;
  float sum = vmat[co * 128 + lane] * s0 * s0 + vmat[co * 128 + 64 + lane] * s1 * s1;
  for (int off = 32; off > 0; off >>= 1) sum += __shfl_down(sum, off, 64);
  if (lane == 0){
    float wn = wnorm[co];
    dco2[pair] = rsqrtf(sum * wn * wn + 1e-8f) * rsqrtf(mag[0]);
  }
}

// per cout: wnorm + vmat[cout][cin]=sum_k cw^2 + bpack (B-frag layout, wn-scaled)
__global__ void k_prep_w(const float* __restrict__ cw, float* __restrict__ wnorm,
                         float* __restrict__ vmat, unsigned short* __restrict__ bpack){
  __shared__ float red[128];
  int co = blockIdx.x, cin = threadIdx.x;
  const float* p = cw + co * 3456 + cin * 27;
  float r[27];
  float v = 0.f;
  #pragma unroll
  for (int k = 0; k < 27; k++){ r[k] = p[k]; v += r[k] * r[k]; }
  vmat[co * 128 + cin] = v;
  red[cin] = v;
  __syncthreads();
  for (int off = 64; off > 0; off >>= 1){
    if (cin < off) red[cin] += red[cin + off];
    __syncthreads();
  }
  float wn_s = rsqrtf(red[0] * (1.0f / 3456.0f));
  if (cin == 0) wnorm[co] = wn_s;
  int grp = co >> 4, m = co & 15;
  int kk = cin >> 5, q = (cin >> 3) & 3, j = cin & 7;
  #pragma unroll
  for (int k = 0; k < 27; k++){
    int idx = ((k * 32 + kk * 8 + grp) * 64 + q * 16 + m) * 8 + j;
    bpack[idx] = f2bf(r[k] * wn_s);
  }
}

// xpad[n][c] = bf16(x[n][c] * sn[b][c]); row NPTS = zeros
__global__ void k_xmod(const float* __restrict__ x, const float* __restrict__ sn,
                       const int* __restrict__ bidx, unsigned short* __restrict__ xpad){
  int gid = blockIdx.x * 256 + threadIdx.x;
  const int total = (NPTS + 1) * 32;
  if (gid >= total) return;
  int n = gid >> 5;
  int c4 = (gid & 31) * 4;
  unsigned short o0, o1, o2, o3;
  if (n < NPTS){
    int b = bidx[n];
    float4 xv = *(const float4*)(x + (size_t)n * CINC + c4);
    float4 sv = *(const float4*)(sn + b * CINC + c4);
    o0 = f2bf(xv.x * sv.x); o1 = f2bf(xv.y * sv.y);
    o2 = f2bf(xv.z * sv.z); o3 = f2bf(xv.w * sv.w);
  } else { o0 = o1 = o2 = o3 = 0; }
  *(ushort4*)(xpad + (size_t)n * CINC + c4) = make_ushort4(o0, o1, o2, o3);
}

// Phase 1: center tap (k=13) is the identity map -> dense GEMM, contiguous A,
// plain f32 stores initialize the raw accumulator in `out` (pre-demod).
__global__ __launch_bounds__(512, 4) void k_center(
    const unsigned short* __restrict__ xpad,
    const unsigned short* __restrict__ bpack,
    float* __restrict__ out){
  __shared__ __align__(16) unsigned short Ash[128 * 128];  // 32KB
  int t = threadIdx.x;
  int wave = t >> 6, lane = t & 63;
  int wm = wave >> 1, wn = wave & 1;
  int q = lane >> 4, m16 = lane & 15;
  int base = blockIdx.x * 128;

  #pragma unroll
  for (int i = 0; i < 4; i++){
    int chunk = i * 512 + t;
    int row = chunk >> 4, c = chunk & 15;
    const unsigned short* src = xpad + (size_t)(base + row) * CINC + ((c ^ row) & 15) * 8;
    GLOAD_LDS16(src, Ash + chunk * 8);
  }

  f32x4 acc[2][4];
  #pragma unroll
  for (int i = 0; i < 2; i++)
    #pragma unroll
    for (int j = 0; j < 4; j++) acc[i][j] = (f32x4){0.f, 0.f, 0.f, 0.f};

  __syncthreads();
  const unsigned short* Bg = bpack + 13 * 16384;
  #pragma unroll
  for (int kk = 0; kk < 4; kk++){
    int cA = ((kk * 4 + q) ^ m16) & 15;
    bf16x8 a0 = *(const bf16x8*)(Ash + (wm * 32 + m16) * 128 + cA * 8);
    bf16x8 a1 = *(const bf16x8*)(Ash + (wm * 32 + 16 + m16) * 128 + cA * 8);
    #pragma unroll
    for (int jn = 0; jn < 4; jn++){
      bf16x8 b = *(const bf16x8*)(Bg + ((kk * 8 + wn * 4 + jn) * 64 + lane) * 8);
      acc[0][jn] = __builtin_amdgcn_mfma_f32_16x16x32_bf16(a0, b, acc[0][jn], 0, 0, 0);
      acc[1][jn] = __builtin_amdgcn_mfma_f32_16x16x32_bf16(a1, b, acc[1][jn], 0, 0, 0);
    }
  }

  #pragma unroll
  for (int i = 0; i < 2; i++)
    #pragma unroll
    for (int r = 0; r < 4; r++){
      int row = wm * 32 + i * 16 + q * 4 + r;
      float* orow = out + (size_t)(base + row) * COUTC;
      #pragma unroll
      for (int jn = 0; jn < 4; jn++)
        orow[wn * 64 + jn * 16 + m16] = acc[i][jn][r];
    }
}

// Phase 2: 26 non-center taps, compact pair lists. Gather A rows via in_idx
// (padding rows = NPTS -> zero row), one K=128 MFMA pass, scatter-accumulate
// into out with HW f32 atomics (rows unique within a tap; cross-tap conflicts
// rare). out_idx valid entries are sorted ascending with NPTS padding after,
// so a tile whose first row is padding is entirely padding -> early exit.
// Full 1024 tiles/tap launched; ~87% exit immediately (no count assumption).
__global__ __launch_bounds__(512, 4) void k_taps(
    const unsigned short* __restrict__ xpad,
    const unsigned short* __restrict__ bpack,
    const int* __restrict__ in_idx,
    const int* __restrict__ out_idx,
    float* __restrict__ out){
  int u = blockIdx.x;
  int kt = u >> 10;
  int tile = u & 1023;
  int k = kt + (kt >= 13);
  const int* ink  = in_idx  + k * NPTS + tile * 128;
  const int* outk = out_idx + k * NPTS + tile * 128;
  if (outk[0] >= NPTS) return;   // sorted list: whole tile is padding

  __shared__ __align__(16) unsigned short Ash[128 * 128];  // 32KB
  int t = threadIdx.x;
  int wave = t >> 6, lane = t & 63;
  int wm = wave >> 1, wn = wave & 1;
  int q = lane >> 4, m16 = lane & 15;

  #pragma unroll
  for (int i = 0; i < 4; i++){
    int chunk = i * 512 + t;
    int row = chunk >> 4, c = chunk & 15;
    int inv = ink[row];
    const unsigned short* src = xpad + (size_t)inv * CINC + ((c ^ row) & 15) * 8;
    GLOAD_LDS16(src, Ash + chunk * 8);
  }

  f32x4 acc[2][4];
  #pragma unroll
  for (int i = 0; i < 2; i++)
    #pragma unroll
    for (int j = 0; j < 4; j++) acc[i][j] = (f32x4){0.f, 0.f, 0.f, 0.f};

  __syncthreads();
  const unsigned short* Bg = bpack + k * 16384;
  #pragma unroll
  for (int kk = 0; kk < 4; kk++){
    int cA = ((kk * 4 + q) ^ m16) & 15;
    bf16x8 a0 = *(const bf16x8*)(Ash + (wm * 32 + m16) * 128 + cA * 8);
    bf16x8 a1 = *(const bf16x8*)(Ash + (wm * 32 + 16 + m16) * 128 + cA * 8);
    #pragma unroll
    for (int jn = 0; jn < 4; jn++){
      bf16x8 b = *(const bf16x8*)(Bg + ((kk * 8 + wn * 4 + jn) * 64 + lane) * 8);
      acc[0][jn] = __builtin_amdgcn_mfma_f32_16x16x32_bf16(a0, b, acc[0][jn], 0, 0, 0);
      acc[1][jn] = __builtin_amdgcn_mfma_f32_16x16x32_bf16(a1, b, acc[1][jn], 0, 0, 0);
    }
  }

  #pragma unroll
  for (int i = 0; i < 2; i++)
    #pragma unroll
    for (int r = 0; r < 4; r++){
      int row = wm * 32 + i * 16 + q * 4 + r;
      int o = outk[row];
      if (o < NPTS){
        float* orow = out + (size_t)o * COUTC;
        #pragma unroll
        for (int jn = 0; jn < 4; jn++)
          unsafeAtomicAdd(&orow[wn * 64 + jn * 16 + m16], acc[i][jn][r]);
      }
    }
}

// Phase 3: demod + bias + leaky*sqrt2 + clip, in-place RMW over out
__global__ void k_epi(float* __restrict__ out, const float* __restrict__ dco2,
                      const float* __restrict__ cbias, const int* __restrict__ bidx){
  int gid = blockIdx.x * 256 + threadIdx.x;
  if (gid >= NPTS * 32) return;
  int n = gid >> 5;
  int c4 = (gid & 31) * 4;
  int b = bidx[n];
  float4 v = *(float4*)(out + (size_t)n * COUTC + c4);
  float4 d = *(const float4*)(dco2 + b * COUTC + c4);
  float4 bi = *(const float4*)(cbias + c4);
  const float S2 = 1.41421356237309515f;
  float r0 = v.x * d.x + bi.x; r0 = (r0 < 0.f ? 0.2f * r0 : r0) * S2; r0 = fminf(fmaxf(r0, -256.f), 256.f);
  float r1 = v.y * d.y + bi.y; r1 = (r1 < 0.f ? 0.2f * r1 : r1) * S2; r1 = fminf(fmaxf(r1, -256.f), 256.f);
  float r2 = v.z * d.z + bi.z; r2 = (r2 < 0.f ? 0.2f * r2 : r2) * S2; r2 = fminf(fmaxf(r2, -256.f), 256.f);
  float r3 = v.w * d.w + bi.w; r3 = (r3 < 0.f ? 0.2f * r3 : r3) * S2; r3 = fminf(fmaxf(r3, -256.f), 256.f);
  *(float4*)(out + (size_t)n * COUTC + c4) = make_float4(r0, r1, r2, r3);
}

extern "C" void kernel_launch(void* const* d_in, const int* in_sizes, int n_in,
                              void* d_out, int out_size, void* d_ws, size_t ws_size,
                              hipStream_t stream){
  const float* x   = (const float*)d_in[0];
  const float* w   = (const float*)d_in[1];
  const float* aw  = (const float*)d_in[2];
  const float* ab  = (const float*)d_in[3];
  const float* cw  = (const float*)d_in[4];
  const float* cb  = (const float*)d_in[5];
  const float* mag = (const float*)d_in[6];
  const int* bidx    = (const int*)d_in[7];
  const int* in_idx  = (const int*)d_in[8];
  const int* out_idx = (const int*)d_in[9];
  float* out = (float*)d_out;
  char* ws = (char*)d_ws;

  float* styles = (float*)(ws + 0);         // 2048 B
  float* sn     = (float*)(ws + 2048);      // 2048 B
  float* wnorm  = (float*)(ws + 4096);      // 512 B
  float* dco2   = (float*)(ws + 4608);      // 2048 B
  float* vmat   = (float*)(ws + 8192);      // 65536 B
  unsigned short* bpack = (unsigned short*)(ws + 73728);    // 884736 B
  unsigned short* xpad  = (unsigned short*)(ws + 958464);   // 33554688 B -> end 34513152

  k_prep_w<<<128, 128, 0, stream>>>(cw, wnorm, vmat, bpack);
  k_styles_dot<<<128, 256, 0, stream>>>(w, aw, ab, styles);
  k_sn_dco<<<64, 512, 0, stream>>>(styles, vmat, wnorm, mag, sn, dco2);
  k_xmod<<<16385, 256, 0, stream>>>(x, sn, bidx, xpad);
  k_center<<<1024, 512, 0, stream>>>(xpad, bpack, out);
  k_taps<<<26 * 1024, 512, 0, stream>>>(xpad, bpack, in_idx, out_idx, out);
  k_epi<<<16384, 256, 0, stream>>>(out, dco2, cb, bidx);
}